// Round 10
// baseline (245.875 us; speedup 1.0000x reference)
//
#include <hip/hip_runtime.h>
#include <hip/hip_bf16.h>

#define KS    21
#define H     192
#define W     192
#define OH    172
#define OW    172
#define CROP  10
#define PLANE (H*W)

#define NCHUNK 7
#define CROWS  3                       // kernel rows per chunk (7*3=21)

#define TXD   16
#define TYD   8
#define TILE_W 32
#define TILE_H 8
#define SROWS (TILE_H + CROWS - 1)     // 10
#define SCOLS (TILE_W + KS - 1)        // 52
#define SCH   (SCOLS / 2)              // 26 (column-parity split)

#define GX    6                        // ceil(172/32) x-tiles
#define GY    22                       // ceil(172/8)  y-tiles
#define NTILES (GX * GY * 4)           // 528 (b, by, bx) tiles

#define CS    (OH * OW)                // 29584
#define OUTN  (4 * 4 * OH * OW)        // one partial span = 473344 floats

__device__ __forceinline__ float softplusf_(float x) {
    // stable: max(x,0) + log(1 + exp(-|x|))
    float e = __expf(-fabsf(x));
    return fmaxf(x, 0.0f) + __logf(1.0f + e);
}

// issue one kraw row's 21 float2 loads into a static register array
#define LOADROW(buf, irow) do {                                              \
    const float* kp_ = kb + (size_t)(i0 + (irow)) * KS * PLANE;              \
    _Pragma("unroll")                                                        \
    for (int j = 0; j < KS; ++j)                                             \
        (buf)[j] = *reinterpret_cast<const float2*>(kp_ + (size_t)j * PLANE);\
} while (0)

// consume one row: softplus + mask + accumulate, rolling LDS window
#define COMPROW(buf, irow) do {                                              \
    const int rr_ = ty + (irow);                                             \
    float4 cur_ = s4[0][rr_][tx];                                            \
    _Pragma("unroll")                                                        \
    for (int j = 0; j < KS; ++j) {                                           \
        float4 nxt_ = s4[(j + 1) & 1][rr_][tx + ((j + 1) >> 1)];             \
        float s0_ = softplusf_((buf)[j].x);                                  \
        float s1_ = softplusf_((buf)[j].y);                                  \
        float km0_ = s0_ * cur_.x;                                           \
        float km1_ = s1_ * nxt_.x;                                           \
        ks0 += km0_;                                                         \
        ks1 += km1_;                                                         \
        a00 = fmaf(km0_, cur_.y, a00);  a01 = fmaf(km1_, nxt_.y, a01);       \
        a10 = fmaf(km0_, cur_.z, a10);  a11 = fmaf(km1_, nxt_.z, a11);       \
        a20 = fmaf(km0_, cur_.w, a20);  a21 = fmaf(km1_, nxt_.w, a21);       \
        cur_ = nxt_;                                                         \
    }                                                                        \
} while (0)

__global__ __launch_bounds__(TXD * TYD, 4)   // cap 128 VGPR -> 4 waves/SIMD
void ar_fused_kernel(const float* __restrict__ kraw,
                     const float* __restrict__ rad,
                     const float* __restrict__ mask,
                     float* __restrict__ part,
                     int* __restrict__ cnt,
                     float* __restrict__ out)
{
    // {mask, r, g, b} per pixel, column-parity split: conflict-free b128 reads
    __shared__ float4 s4[2][SROWS][SCH];
    __shared__ int s_last;

    const int zz    = blockIdx.z;          // grid.z = 4*NCHUNK = 28
    const int b     = zz & 3;
    const int chunk = zz >> 2;
    const int i0    = chunk * CROWS;
    const int tileid = (b * GY + blockIdx.y) * GX + blockIdx.x;  // chunk-indep

    // x-origin shifted by -CROP: each block's kraw byte range per row is
    // [128*bx, 128*bx+128) — whole cache lines, no straddle (R7 lesson)
    const int x0t = blockIdx.x * TILE_W - CROP;
    const int y0t = blockIdx.y * TILE_H;
    const int tx  = threadIdx.x, ty = threadIdx.y;
    const int tid = ty * TXD + tx;

    const int x0 = x0t + tx * 2;               // even; may be <0 or >=OW
    const int y  = y0t + ty;

    // kraw col = 32*bx + 2*tx (in-plane); rows y+CROP <= 185. Overshoot
    // threads compute garbage, never store.
    const float* kb = kraw + (size_t)b * KS * KS * PLANE
                           + (size_t)(y + CROP) * W + (x0 + CROP);

    // ---- issue first 2 row-bursts BEFORE staging: 21KB/wave in flight
    // during the staging loads + barrier (registers already budgeted)
    float2 kva[KS], kvb[KS];
    LOADROW(kva, 0);
    LOADROW(kvb, 1);

    // ---- stage mask + radiance rows [y0t+i0 .. y0t+i0+SROWS-1] ----
    const float* mbase = mask + (size_t)b * PLANE;
    const float* rbase = rad  + (size_t)b * 3 * PLANE;
    for (int t = tid; t < SROWS * SCOLS; t += TXD * TYD) {
        int rr = t / SCOLS, cc = t - rr * SCOLS;
        int gr = min(y0t + i0 + rr, H - 1);          // clamped rows/cols only
        int gc = min(max(x0t + cc, 0), W - 1);       // feed unstored outputs
        int off = gr * W + gc;
        float4 v;
        v.x = mbase[off];
        v.y = rbase[off];
        v.z = rbase[off + PLANE];
        v.w = rbase[off + 2 * PLANE];
        s4[cc & 1][rr][cc >> 1] = v;
    }
    __syncthreads();

    float ks0 = 0.f, ks1 = 0.f;
    float a00 = 0.f, a01 = 0.f;
    float a10 = 0.f, a11 = 0.f;
    float a20 = 0.f, a21 = 0.f;

    // 2-deep software pipeline (R3/R7 proven)
    COMPROW(kva, 0);
    LOADROW(kva, 2);
    COMPROW(kvb, 1);
    COMPROW(kva, 2);

    // ---- store partial span (layout mirrors final out) ----
    const bool valid = (y < OH) & (x0 >= 0) & (x0 < OW);
    const size_t wbase = ((size_t)b * 3 * OH + y) * OW + x0;
    const size_t kbase = (size_t)12 * CS + ((size_t)b * OH + y) * OW + x0;
    if (valid) {
        float* pb = part + (size_t)chunk * OUTN;
        *reinterpret_cast<float2*>(pb + wbase)          = make_float2(a00, a01);
        *reinterpret_cast<float2*>(pb + wbase + CS)     = make_float2(a10, a11);
        *reinterpret_cast<float2*>(pb + wbase + 2 * CS) = make_float2(a20, a21);
        *reinterpret_cast<float2*>(pb + kbase)          = make_float2(ks0, ks1);
    }

    // ---- last-finisher reduction (no spin: no dispatch-order assumption) ----
    __syncthreads();                       // drains vmcnt(0) -> stores complete
    if (tid == 0) {
        __threadfence();                   // release partials device-wide
        int old = atomicAdd(&cnt[tileid], 1);
        s_last = (old == NCHUNK - 1);
    }
    __syncthreads();
    if (s_last) {
        __threadfence();                   // acquire before reading spans
        if (valid) {
            float2 r0 = make_float2(0.f, 0.f), r1 = r0, r2 = r0, rk = r0;
            // fixed k-order sum (bitwise-deterministic regardless of which
            // chunk's block performs the reduction)
            #pragma unroll
            for (int k = 0; k < NCHUNK; ++k) {
                const float* pk = part + (size_t)k * OUTN;
                float2 v;
                v = *reinterpret_cast<const float2*>(pk + wbase);
                r0.x += v.x; r0.y += v.y;
                v = *reinterpret_cast<const float2*>(pk + wbase + CS);
                r1.x += v.x; r1.y += v.y;
                v = *reinterpret_cast<const float2*>(pk + wbase + 2 * CS);
                r2.x += v.x; r2.y += v.y;
                v = *reinterpret_cast<const float2*>(pk + kbase);
                rk.x += v.x; rk.y += v.y;
            }
            *reinterpret_cast<float2*>(out + wbase)          = r0;
            *reinterpret_cast<float2*>(out + wbase + CS)     = r1;
            *reinterpret_cast<float2*>(out + wbase + 2 * CS) = r2;
            *reinterpret_cast<float2*>(out + kbase)          = rk;
        }
    }
}

extern "C" void kernel_launch(void* const* d_in, const int* in_sizes, int n_in,
                              void* d_out, int out_size, void* d_ws, size_t ws_size,
                              hipStream_t stream) {
    const float* kraw = (const float*)d_in[0];   // [4,441,192,192] f32
    const float* rad  = (const float*)d_in[1];   // [4,3,192,192]   f32
    const float* mask = (const float*)d_in[2];   // [4,1,192,192]   f32
    float* out  = (float*)d_out;                 // ws[4,3,172,172] ++ ks[4,1,172,172]
    float* part = (float*)d_ws;                  // NCHUNK spans of OUTN floats
    int*   cnt  = (int*)((char*)d_ws + (size_t)NCHUNK * OUTN * sizeof(float));

    hipMemsetAsync(cnt, 0, NTILES * sizeof(int), stream);

    dim3 block(TXD, TYD, 1);
    dim3 grid(GX, GY, 4 * NCHUNK);
    hipLaunchKernelGGL(ar_fused_kernel, grid, block, 0, stream,
                       kraw, rad, mask, part, cnt, out);
}

// Round 11
// 69.833 us; speedup vs baseline: 3.5209x; 3.5209x over previous
//
#include <hip/hip_runtime.h>
#include <hip/hip_bf16.h>

#define KS    21
#define H     192
#define W     192
#define OH    172
#define OW    172
#define CROP  10
#define PLANE (H*W)

#define NCHUNK 7
#define CROWS  3                       // kernel rows per chunk (7*3=21)

#define TXD   16
#define TYD   8
#define TILE_W 32
#define TILE_H 8
#define SROWS (TILE_H + CROWS - 1)     // 10
#define SCOLS (TILE_W + KS - 1)        // 52
#define SCH   (SCOLS / 2)              // 26 (column-parity split)

#define CS    (OH * OW)                // 29584
#define OUTN  (4 * 4 * OH * OW)        // one partial span = 473344 floats

typedef float v2f __attribute__((ext_vector_type(2)));

__device__ __forceinline__ float softplusf_(float x) {
    // stable: max(x,0) + log(1 + exp(-|x|))
    float e = __expf(-fabsf(x));
    return fmaxf(x, 0.0f) + __logf(1.0f + e);
}

// issue one kraw row's 21 float2 loads into a static register array.
// NONTEMPORAL: kraw lines are strictly single-use; stream policy stops them
// from thrashing the 4MB/XCD L2 (theory under test this round).
#define LOADROW(buf, irow) do {                                              \
    const float* kp_ = kb + (size_t)(i0 + (irow)) * KS * PLANE;              \
    _Pragma("unroll")                                                        \
    for (int j = 0; j < KS; ++j)                                             \
        (buf)[j] = __builtin_nontemporal_load(                               \
            reinterpret_cast<const v2f*>(kp_ + (size_t)j * PLANE));          \
} while (0)

// consume one row: softplus + mask + accumulate, rolling LDS window
#define COMPROW(buf, irow) do {                                              \
    const int rr_ = ty + (irow);                                             \
    float4 cur_ = s4[0][rr_][tx];                                            \
    _Pragma("unroll")                                                        \
    for (int j = 0; j < KS; ++j) {                                           \
        float4 nxt_ = s4[(j + 1) & 1][rr_][tx + ((j + 1) >> 1)];             \
        float s0_ = softplusf_((buf)[j].x);                                  \
        float s1_ = softplusf_((buf)[j].y);                                  \
        float km0_ = s0_ * cur_.x;                                           \
        float km1_ = s1_ * nxt_.x;                                           \
        ks0 += km0_;                                                         \
        ks1 += km1_;                                                         \
        a00 = fmaf(km0_, cur_.y, a00);  a01 = fmaf(km1_, nxt_.y, a01);       \
        a10 = fmaf(km0_, cur_.z, a10);  a11 = fmaf(km1_, nxt_.z, a11);       \
        a20 = fmaf(km0_, cur_.w, a20);  a21 = fmaf(km1_, nxt_.w, a21);       \
        cur_ = nxt_;                                                         \
    }                                                                        \
} while (0)

__global__ __launch_bounds__(TXD * TYD, 4)   // cap 128 VGPR -> 4 waves/SIMD
void ar_partial_kernel(const float* __restrict__ kraw,
                       const float* __restrict__ rad,
                       const float* __restrict__ mask,
                       float* __restrict__ part)
{
    // {mask, r, g, b} per pixel, split by column parity: 16-lane reads are
    // 16B-stride contiguous (conflict-free b128 pattern).
    __shared__ float4 s4[2][SROWS][SCH];

    const int zz    = blockIdx.z;          // grid.z = 4*NCHUNK = 28
    const int b     = zz & 3;
    const int chunk = zz >> 2;
    const int i0    = chunk * CROWS;

    // x-origin shifted by -CROP so each block's kraw byte range per row is
    // [128*bx, 128*bx+128): whole cache lines, no straddle (R7 lesson).
    const int x0t = blockIdx.x * TILE_W - CROP;
    const int y0t = blockIdx.y * TILE_H;
    const int tx  = threadIdx.x, ty = threadIdx.y;
    const int tid = ty * TXD + tx;

    // ---- stage mask + radiance for input rows [y0t+i0 .. y0t+i0+SROWS-1] ----
    const float* mbase = mask + (size_t)b * PLANE;
    const float* rbase = rad  + (size_t)b * 3 * PLANE;
    for (int t = tid; t < SROWS * SCOLS; t += TXD * TYD) {
        int rr = t / SCOLS, cc = t - rr * SCOLS;
        int gr = min(y0t + i0 + rr, H - 1);          // clamped rows/cols only
        int gc = min(max(x0t + cc, 0), W - 1);       // feed unstored outputs
        int off = gr * W + gc;
        float4 v;
        v.x = mbase[off];
        v.y = rbase[off];
        v.z = rbase[off + PLANE];
        v.w = rbase[off + 2 * PLANE];
        s4[cc & 1][rr][cc >> 1] = v;
    }
    __syncthreads();

    const int x0 = x0t + tx * 2;               // even; may be negative or >=OW
    const int y  = y0t + ty;

    // kraw col = x0 + CROP = 32*bx + 2*tx  (>= 0, <= 191): always in-plane.
    // Rows y+CROP <= 185. Overshoot threads compute garbage, never store.
    const float* kb = kraw + (size_t)b * KS * KS * PLANE
                           + (size_t)(y + CROP) * W + (x0 + CROP);

    float ks0 = 0.f, ks1 = 0.f;
    float a00 = 0.f, a01 = 0.f;
    float a10 = 0.f, a11 = 0.f;
    float a20 = 0.f, a21 = 0.f;

    // software-pipelined rows: up to 2 rows (42 loads) in flight per wave
    v2f kva[KS], kvb[KS];
    LOADROW(kva, 0);
    LOADROW(kvb, 1);
    COMPROW(kva, 0);
    LOADROW(kva, 2);
    COMPROW(kvb, 1);
    COMPROW(kva, 2);

    // ---- store partial, layout mirroring final out, offset by chunk*OUTN ----
    if (y < OH && x0 >= 0 && x0 < OW) {    // x0 even => x0+1 also in range
        float* pb = part + (size_t)chunk * OUTN;
        const size_t wbase = ((size_t)b * 3 * OH + y) * OW + x0;
        const size_t kbase = (size_t)12 * CS + ((size_t)b * OH + y) * OW + x0;
        *reinterpret_cast<float2*>(pb + wbase)          = make_float2(a00, a01);
        *reinterpret_cast<float2*>(pb + wbase + CS)     = make_float2(a10, a11);
        *reinterpret_cast<float2*>(pb + wbase + 2 * CS) = make_float2(a20, a21);
        *reinterpret_cast<float2*>(pb + kbase)          = make_float2(ks0, ks1);
    }
}

__global__ __launch_bounds__(256)
void ar_reduce_kernel(const float* __restrict__ part, float* __restrict__ out)
{
    int i = blockIdx.x * 256 + threadIdx.x;      // over OUTN/4 float4s
    if (i < OUTN / 4) {
        const float4* p4 = reinterpret_cast<const float4*>(part);
        float4 r = p4[i];
        #pragma unroll
        for (int k = 1; k < NCHUNK; ++k) {
            float4 v = p4[i + (size_t)k * (OUTN / 4)];
            r.x += v.x; r.y += v.y; r.z += v.z; r.w += v.w;
        }
        reinterpret_cast<float4*>(out)[i] = r;
    }
}

extern "C" void kernel_launch(void* const* d_in, const int* in_sizes, int n_in,
                              void* d_out, int out_size, void* d_ws, size_t ws_size,
                              hipStream_t stream) {
    const float* kraw = (const float*)d_in[0];   // [4,441,192,192] f32
    const float* rad  = (const float*)d_in[1];   // [4,3,192,192]   f32
    const float* mask = (const float*)d_in[2];   // [4,1,192,192]   f32
    float* out  = (float*)d_out;                 // ws[4,3,172,172] ++ ks[4,1,172,172]
    float* part = (float*)d_ws;                  // NCHUNK partials of OUTN floats

    dim3 block(TXD, TYD, 1);
    dim3 grid((OW + TILE_W - 1) / TILE_W, (OH + TILE_H - 1) / TILE_H, 4 * NCHUNK);
    hipLaunchKernelGGL(ar_partial_kernel, grid, block, 0, stream,
                       kraw, rad, mask, part);

    int n4 = OUTN / 4;
    hipLaunchKernelGGL(ar_reduce_kernel, dim3((n4 + 255) / 256), dim3(256), 0, stream,
                       part, out);
}

// Round 12
// 59.864 us; speedup vs baseline: 4.1072x; 1.1665x over previous
//
#include <hip/hip_runtime.h>
#include <hip/hip_bf16.h>

#define KS    21
#define H     192
#define W     192
#define OH    172
#define OW    172
#define CROP  10
#define PLANE (H*W)

#define NCHUNK 7
#define CROWS  3                       // kernel rows per chunk (7*3=21)

#define TXD   16
#define TYD   16
#define TILE_W 32
#define TILE_H 16
#define SROWS (TILE_H + CROWS - 1)     // 18
#define SCOLS (TILE_W + KS - 1)        // 52
#define SCH   (SCOLS / 2)              // 26 (column-parity split)

#define CS    (OH * OW)                // 29584
#define OUTN  (4 * 4 * OH * OW)        // one partial span = 473344 floats

__device__ __forceinline__ float softplusf_(float x) {
    // stable: max(x,0) + log(1 + exp(-|x|))
    float e = __expf(-fabsf(x));
    return fmaxf(x, 0.0f) + __logf(1.0f + e);
}

// issue one kraw row's 21 float2 loads into a static register array
#define LOADROW(buf, irow) do {                                              \
    const float* kp_ = kb + (size_t)(i0 + (irow)) * KS * PLANE;              \
    _Pragma("unroll")                                                        \
    for (int j = 0; j < KS; ++j)                                             \
        (buf)[j] = *reinterpret_cast<const float2*>(kp_ + (size_t)j * PLANE);\
} while (0)

// consume one row: softplus + mask + accumulate, rolling LDS window
#define COMPROW(buf, irow) do {                                              \
    const int rr_ = ty + (irow);                                             \
    float4 cur_ = s4[0][rr_][tx];                                            \
    _Pragma("unroll")                                                        \
    for (int j = 0; j < KS; ++j) {                                           \
        float4 nxt_ = s4[(j + 1) & 1][rr_][tx + ((j + 1) >> 1)];             \
        float s0_ = softplusf_((buf)[j].x);                                  \
        float s1_ = softplusf_((buf)[j].y);                                  \
        float km0_ = s0_ * cur_.x;                                           \
        float km1_ = s1_ * nxt_.x;                                           \
        ks0 += km0_;                                                         \
        ks1 += km1_;                                                         \
        a00 = fmaf(km0_, cur_.y, a00);  a01 = fmaf(km1_, nxt_.y, a01);       \
        a10 = fmaf(km0_, cur_.z, a10);  a11 = fmaf(km1_, nxt_.z, a11);       \
        a20 = fmaf(km0_, cur_.w, a20);  a21 = fmaf(km1_, nxt_.w, a21);       \
        cur_ = nxt_;                                                         \
    }                                                                        \
} while (0)

__global__ __launch_bounds__(TXD * TYD, 4)   // cap 128 VGPR -> 4 waves/SIMD
void ar_partial_kernel(const float* __restrict__ kraw,
                       const float* __restrict__ rad,
                       const float* __restrict__ mask,
                       float* __restrict__ part)
{
    // {mask, r, g, b} per pixel, split by column parity: 16-lane reads are
    // 16B-stride contiguous (conflict-free b128 pattern).
    __shared__ float4 s4[2][SROWS][SCH];

    const int zz    = blockIdx.z;          // grid.z = 4*NCHUNK = 28
    const int b     = zz & 3;
    const int chunk = zz >> 2;
    const int i0    = chunk * CROWS;

    // x-origin shifted by -CROP so each block's kraw byte range per row is
    // [128*bx, 128*bx+128): whole cache lines, no straddle (R7 lesson).
    const int x0t = blockIdx.x * TILE_W - CROP;
    const int y0t = blockIdx.y * TILE_H;
    const int tx  = threadIdx.x, ty = threadIdx.y;
    const int tid = ty * TXD + tx;

    // ---- stage mask + radiance for input rows [y0t+i0 .. y0t+i0+SROWS-1] ----
    const float* mbase = mask + (size_t)b * PLANE;
    const float* rbase = rad  + (size_t)b * 3 * PLANE;
    for (int t = tid; t < SROWS * SCOLS; t += TXD * TYD) {
        int rr = t / SCOLS, cc = t - rr * SCOLS;
        int gr = min(y0t + i0 + rr, H - 1);          // clamped rows/cols only
        int gc = min(max(x0t + cc, 0), W - 1);       // feed unstored outputs
        int off = gr * W + gc;
        float4 v;
        v.x = mbase[off];
        v.y = rbase[off];
        v.z = rbase[off + PLANE];
        v.w = rbase[off + 2 * PLANE];
        s4[cc & 1][rr][cc >> 1] = v;
    }
    __syncthreads();

    const int x0 = x0t + tx * 2;               // even; may be negative or >=OW
    const int y  = y0t + ty;

    // kraw col = x0 + CROP = 32*bx + 2*tx  (>= 0, <= 191): always in-plane.
    // Rows y+CROP <= 185 for stored outputs; overshoot threads (y>=OH in the
    // last y-tile) stay in-plane (y+CROP <= 185+... max y = 175 -> 185+0)
    // actually max y = 11*16-1+0 = 175 < 182 -> y+CROP <= 185: in-plane.
    const float* kb = kraw + (size_t)b * KS * KS * PLANE
                           + (size_t)(y + CROP) * W + (x0 + CROP);

    float ks0 = 0.f, ks1 = 0.f;
    float a00 = 0.f, a01 = 0.f;
    float a10 = 0.f, a11 = 0.f;
    float a20 = 0.f, a21 = 0.f;

    // software-pipelined rows: up to 2 rows (42 loads) in flight per wave
    float2 kva[KS], kvb[KS];
    LOADROW(kva, 0);
    LOADROW(kvb, 1);
    COMPROW(kva, 0);
    LOADROW(kva, 2);
    COMPROW(kvb, 1);
    COMPROW(kva, 2);

    // ---- store partial, layout mirroring final out, offset by chunk*OUTN ----
    if (y < OH && x0 >= 0 && x0 < OW) {    // x0 even => x0+1 also in range
        float* pb = part + (size_t)chunk * OUTN;
        const size_t wbase = ((size_t)b * 3 * OH + y) * OW + x0;
        const size_t kbase = (size_t)12 * CS + ((size_t)b * OH + y) * OW + x0;
        *reinterpret_cast<float2*>(pb + wbase)          = make_float2(a00, a01);
        *reinterpret_cast<float2*>(pb + wbase + CS)     = make_float2(a10, a11);
        *reinterpret_cast<float2*>(pb + wbase + 2 * CS) = make_float2(a20, a21);
        *reinterpret_cast<float2*>(pb + kbase)          = make_float2(ks0, ks1);
    }
}

__global__ __launch_bounds__(256)
void ar_reduce_kernel(const float* __restrict__ part, float* __restrict__ out)
{
    int i = blockIdx.x * 256 + threadIdx.x;      // over OUTN/4 float4s
    if (i < OUTN / 4) {
        const float4* p4 = reinterpret_cast<const float4*>(part);
        float4 r = p4[i];
        #pragma unroll
        for (int k = 1; k < NCHUNK; ++k) {
            float4 v = p4[i + (size_t)k * (OUTN / 4)];
            r.x += v.x; r.y += v.y; r.z += v.z; r.w += v.w;
        }
        reinterpret_cast<float4*>(out)[i] = r;
    }
}

extern "C" void kernel_launch(void* const* d_in, const int* in_sizes, int n_in,
                              void* d_out, int out_size, void* d_ws, size_t ws_size,
                              hipStream_t stream) {
    const float* kraw = (const float*)d_in[0];   // [4,441,192,192] f32
    const float* rad  = (const float*)d_in[1];   // [4,3,192,192]   f32
    const float* mask = (const float*)d_in[2];   // [4,1,192,192]   f32
    float* out  = (float*)d_out;                 // ws[4,3,172,172] ++ ks[4,1,172,172]
    float* part = (float*)d_ws;                  // NCHUNK partials of OUTN floats

    dim3 block(TXD, TYD, 1);
    dim3 grid((OW + TILE_W - 1) / TILE_W, (OH + TILE_H - 1) / TILE_H, 4 * NCHUNK);
    hipLaunchKernelGGL(ar_partial_kernel, grid, block, 0, stream,
                       kraw, rad, mask, part);

    int n4 = OUTN / 4;
    hipLaunchKernelGGL(ar_reduce_kernel, dim3((n4 + 255) / 256), dim3(256), 0, stream,
                       part, out);
}